// Round 5
// baseline (790.752 us; speedup 1.0000x reference)
//
#include <hip/hip_runtime.h>

// CRF NLL: B=256 batches, S=2048 steps, T=64 tags.
// One wave per batch (lane = tag). Exp-space forward recurrence.
// Broadcast of q: f16 pair pack + 32x ds_bpermute (register crossbar, LDS pipe,
// no memory round trip). Dot: 32x v_pk_fma_f16. Renorm scale folded into the
// NEXT step's emission factor so bit-math renorm runs off the critical path.
#define BB 256
#define SS 2048
#define TT 64

typedef __fp16 half2v __attribute__((ext_vector_type(2)));

__device__ __forceinline__ float rfl_f(float x) {
  return __builtin_bit_cast(float, __builtin_amdgcn_readfirstlane(__builtin_bit_cast(int, x)));
}

// neighbor swap within lane pairs (quad_perm [1,0,3,2] = 0xB1)
__device__ __forceinline__ float dpp_swap1(float x) {
  int r = __builtin_amdgcn_update_dpp(0, __builtin_bit_cast(int, x), 0xB1, 0xF, 0xF, true);
  return __builtin_bit_cast(float, r);
}

__device__ __forceinline__ half2v i2h2(int x) { return __builtin_bit_cast(half2v, x); }

// Invariant: alpha_j = ln2 * (log2(t_j) + gamma0 + esum - 116*nsteps), where
// t is the unnormalized scaled state, sc = 2^(121-e_prev) is applied lazily to
// the next step's emission factor, and esum accumulates e at consumption time.
// E2[c] = (exp(trans[2c][j]), exp(trans[2c+1][j])) * 2^-5 (f16 pair, lane's j).
__device__ __forceinline__ void crf_step(float& t, float& sc, int& epend, int& esum,
                                         float x, const half2v (&E2)[32],
                                         const int (&ba)[32]) {
  float xs = x * sc;                    // sc uniform (SGPR); off critical path
  esum += epend;                        // consume pending exponent (SALU)
  float tn = dpp_swap1(t);
  int qpi = __builtin_bit_cast(int, __builtin_amdgcn_cvt_pkrtz(t, tn));  // even lanes valid
  int qraw[32];
#pragma unroll
  for (int c = 0; c < 32; ++c)
    qraw[c] = __builtin_amdgcn_ds_bpermute(ba[c], qpi);  // broadcast pair c
  half2v a0 = (half2v)0, a1 = (half2v)0, a2 = (half2v)0, a3 = (half2v)0;
#pragma unroll
  for (int m = 0; m < 8; ++m) {
    a0 += i2h2(qraw[4 * m + 0]) * E2[4 * m + 0];
    a1 += i2h2(qraw[4 * m + 1]) * E2[4 * m + 1];
    a2 += i2h2(qraw[4 * m + 2]) * E2[4 * m + 2];
    a3 += i2h2(qraw[4 * m + 3]) * E2[4 * m + 3];
  }
  half2v s = (a0 + a1) + (a2 + a3);
  float y = (float)s[0] + (float)s[1];
  t = y * xs;                           // > 0 always
  int eb = __builtin_bit_cast(int, rfl_f(t)) & 0x7f800000;
  epend = eb >> 23;                     // this step's exponent, consumed next step
  sc = __builtin_bit_cast(float, 0x7C000000 - eb);  // 2^(121-e), exact
}

__device__ __forceinline__ void prefetch8(float (&buf)[8], int& mreg, float& tvg,
                                          float& evg, int i0,
                                          const float* __restrict__ ep,
                                          const float* __restrict__ emb,
                                          const int* __restrict__ mp,
                                          const int* __restrict__ tg,
                                          const float* __restrict__ trans, int j) {
#pragma unroll
  for (int t = 0; t < 8; ++t) {
    int ii = i0 + t;
    ii = ii > SS - 1 ? SS - 1 : ii;     // clamp: harmless dup load
    buf[t] = ep[ii * TT];
  }
  int mi = i0 + (j & 7);
  int mc = mi > SS - 1 ? SS - 1 : mi;
  mreg = (mi > SS - 1) ? 0 : mp[mc];    // OOB steps masked off
  tvg = 0.f;
  evg = 0.f;
  if (j < 8) {                          // numerator gathers for this block's 8 steps
    int tgc = tg[mc];
    int tgp = tg[mc - 1];               // mc >= 1 always (i0 >= 1)
    tvg = trans[tgp * TT + tgc];
    evg = emb[(size_t)mc * TT + tgc];
  }
}

__device__ __forceinline__ void process8(float& t, float& sc, int& epend, int& esum,
                                         int& nsteps, const float (&buf)[8], int mreg,
                                         const half2v (&E2)[32], const int (&ba)[32]) {
  unsigned long long bal = __ballot(mreg != 0);
  if (bal == ~0ull) {                   // fast path: all 8 steps active
    float xs[8];
#pragma unroll
    for (int k = 0; k < 8; ++k) xs[k] = __expf(buf[k]);
#pragma unroll
    for (int k = 0; k < 8; ++k) crf_step(t, sc, epend, esum, xs[k], E2, ba);
    nsteps += 8;
  } else {                              // rare: per-step uniform branch
#pragma unroll
    for (int k = 0; k < 8; ++k) {
      int mv = __builtin_amdgcn_readlane(mreg, k);
      if (mv) {
        crf_step(t, sc, epend, esum, __expf(buf[k]), E2, ba);
        nsteps += 1;
      }
    }
  }
}

__global__ __launch_bounds__(64, 1) void crf_kernel(
    const float* __restrict__ em, const float* __restrict__ startT,
    const float* __restrict__ endT, const float* __restrict__ trans,
    const int* __restrict__ tags, const int* __restrict__ mask,
    float* __restrict__ out) {
  const int b = blockIdx.x;
  const int j = threadIdx.x;            // tag index, one wave per batch

  half2v E2[32];
#pragma unroll
  for (int m = 0; m < 32; ++m) {
    float e0 = __expf(trans[(2 * m) * TT + j]) * 0.03125f;
    float e1 = __expf(trans[(2 * m + 1) * TT + j]) * 0.03125f;
    E2[m] = __builtin_amdgcn_cvt_pkrtz(e0, e1);
  }

  // bpermute addresses: pair c lives on lane 2c -> byte addr 8c. Pin each in a
  // VGPR (asm) so the compiler can't rematerialize 32 v_movs per step.
  int ba[32];
#pragma unroll
  for (int c = 0; c < 32; ++c) {
    int a = 8 * c;
    asm("" : "+v"(a));
    ba[c] = a;
  }

  const float* emb = em + (size_t)b * SS * TT;
  const float* ep = emb + j;
  const int* mp = mask + b * SS;
  const int* tg = tags + b * SS;

  // init: alpha0 = start + em[0]; t = exp(alpha0 - alpha0[0]) * 2^-6
  float a0v = startT[j] + ep[0];
  float a00 = rfl_f(a0v);
  float t = __expf(a0v - a00) * 0.015625f;
  float gamma0 = a00 * 1.4426950408889634f + 6.0f;
  float sc = 1.0f;                      // 2^(121-121): t already normalized
  int epend = 121, esum = 0, nsteps = 0;

  // numerator partial: step-0 term on lane 0
  int tg0 = tg[0];
  float pnum = 0.f;
  if (j == 0) pnum = startT[tg0] + emb[tg0];

  // steps i = 1..2047 as 256 chunks of 8 (chunk 255 pads step 2048, masked off)
  float bufA[8], bufB[8];
  int mA, mB;
  float tvA, evA, tvB, evB;
  prefetch8(bufA, mA, tvA, evA, 1, ep, emb, mp, tg, trans, j);
  for (int c = 0; c < 256; c += 2) {
    prefetch8(bufB, mB, tvB, evB, 1 + 8 * (c + 1), ep, emb, mp, tg, trans, j);
    process8(t, sc, epend, esum, nsteps, bufA, mA, E2, ba);
    pnum += (mA != 0) ? (tvA + evA) : 0.f;   // lanes >=8 carry zeros
    prefetch8(bufA, mA, tvA, evA, 1 + 8 * (c + 2), ep, emb, mp, tg, trans, j);
    process8(t, sc, epend, esum, nsteps, bufB, mB, E2, ba);
    pnum += (mB != 0) ? (tvB + evB) : 0.f;
  }

  // denominator = logsumexp_j(alpha_j + end_j)
  float gamma = gamma0 + (float)esum - 116.0f * (float)nsteps;
  float alpha = (__log2f(t) + gamma) * 0.69314718055994531f;
  float tj = alpha + endT[j];
  float mx = tj;
#pragma unroll
  for (int o = 32; o > 0; o >>= 1) mx = fmaxf(mx, __shfl_xor(mx, o, 64));
  float ex = __expf(tj - mx);
#pragma unroll
  for (int o = 32; o > 0; o >>= 1) ex += __shfl_xor(ex, o, 64);
  float den = mx + __logf(ex);

  // numerator total: sum lanes' partials (only 0-7 nonzero)
  float nsum = pnum;
#pragma unroll
  for (int o = 32; o > 0; o >>= 1) nsum += __shfl_xor(nsum, o, 64);

  if (j == 0) {
    int lastTag = tg[nsteps];           // seq_len-1 == nsteps
    float nm = nsum + endT[lastTag];
    atomicAdd(out, (den - nm) * (1.0f / BB));
  }
}

extern "C" void kernel_launch(void* const* d_in, const int* in_sizes, int n_in,
                              void* d_out, int out_size, void* d_ws, size_t ws_size,
                              hipStream_t stream) {
  const float* em = (const float*)d_in[0];
  const float* startT = (const float*)d_in[1];
  const float* endT = (const float*)d_in[2];
  const float* trans = (const float*)d_in[3];
  const int* tags = (const int*)d_in[4];
  const int* mask = (const int*)d_in[5];
  float* out = (float*)d_out;

  (void)hipMemsetAsync(out, 0, sizeof(float), stream);
  crf_kernel<<<BB, 64, 0, stream>>>(em, startT, endT, trans, tags, mask, out);
}

// Round 6
// 263.768 us; speedup vs baseline: 2.9979x; 2.9979x over previous
//
#include <hip/hip_runtime.h>

// CRF NLL: B=256, S=2048, T=64.
// Sequence-parallel forward algorithm: each batch split into KC=16 chunks.
// Positive-matrix products contract directions (Birkhoff: <=tanh(1)=0.762/step,
// independent of emissions), so each chunk starts from a uniform vector, runs
// WARM=48 warmup steps over the previous chunk's tail to converge to the true
// direction (error ~1e-5), then accumulates its chunk's log-scale growth V_c.
// log Z = sum_c V_c + final logsumexp. 4096 waves = 4/SIMD hides the ~600-cyc
// per-step LDS-broadcast critical path; kernel becomes issue-bound (~194 cyc).
#define BB 256
#define SS 2048
#define TT 64
#define KC 16          // chunks per batch
#define LC (SS / KC)   // 128 main steps per chunk
#define WARM 48        // warmup steps = 6 blocks of 8

typedef __fp16 half2v __attribute__((ext_vector_type(2)));
typedef __fp16 half8v __attribute__((ext_vector_type(8)));

__device__ __forceinline__ float rfl_f(float x) {
  return __builtin_bit_cast(float, __builtin_amdgcn_readfirstlane(__builtin_bit_cast(int, x)));
}

// Invariant: alpha_j = ln2 * (log2(q_j) + gamma), q_0 in [2^-6, 2^-5).
// E2[c] = (exp(trans[2c][j]), exp(trans[2c+1][j])) * 2^-5 (f16 pair, lane's j).
// gamma = gamma0 + esum - 116*nsteps (exact integer bookkeeping).
__device__ __forceinline__ void crf_step(float& q, int& esum, float x,
                                         const half2v (&E2)[32],
                                         __fp16* qsh, int j) {
  const half8v* qv = (const half8v*)qsh;
  half2v a0 = (half2v)0, a1 = (half2v)0, a2 = (half2v)0, a3 = (half2v)0;
#pragma unroll
  for (int m = 0; m < 8; ++m) {
    half8v blk = qv[m];  // q[8m..8m+7], one ds_read_b128 (broadcast)
    a0 += __builtin_shufflevector(blk, blk, 0, 1) * E2[4 * m + 0];
    a1 += __builtin_shufflevector(blk, blk, 2, 3) * E2[4 * m + 1];
    a2 += __builtin_shufflevector(blk, blk, 4, 5) * E2[4 * m + 2];
    a3 += __builtin_shufflevector(blk, blk, 6, 7) * E2[4 * m + 3];
  }
  half2v s = (a0 + a1) + (a2 + a3);
  float y = (float)s[0] + (float)s[1];
  float t = y * x;                      // > 0 always
  float v = rfl_f(t);                   // lane-0 value, uniform
  int eb = __builtin_bit_cast(int, v) & 0x7f800000;
  float scale = __builtin_bit_cast(float, 0x7C000000 - eb);  // 2^(121-e), exact
  q = t * scale;                        // q_0 back in [2^-6, 2^-5)
  esum += (eb >> 23);                   // exact exponent bookkeeping
  qsh[j] = (__fp16)q;                   // publish for next step
}

__device__ __forceinline__ void prefetch8(float (&buf)[8], int& mreg, float& tvg,
                                          float& evg, int i0, bool gather,
                                          const float* __restrict__ ep,
                                          const float* __restrict__ emb,
                                          const int* __restrict__ mp,
                                          const int* __restrict__ tg,
                                          const float* __restrict__ trans, int j) {
#pragma unroll
  for (int t = 0; t < 8; ++t) {
    int ii = i0 + t;
    ii = ii > SS - 1 ? SS - 1 : ii;     // clamp: harmless dup load
    ii = ii < 0 ? 0 : ii;
    buf[t] = ep[ii * TT];
  }
  int mi = i0 + (j & 7);
  int mc = mi > SS - 1 ? SS - 1 : mi;
  mc = mc < 1 ? 1 : mc;
  mreg = (mi > SS - 1 || mi < 1) ? 0 : mp[mc];  // OOB slots masked off
  tvg = 0.f;
  evg = 0.f;
  if (gather && j < 8) {                // numerator gathers (main blocks only)
    int tgc = tg[mc];
    int tgp = tg[mc - 1];
    tvg = trans[tgp * TT + tgc];
    evg = emb[(size_t)mc * TT + tgc];
  }
}

__device__ __forceinline__ void process8(float& q, int& esum, int& nsteps,
                                         const float (&buf)[8], int mreg,
                                         const half2v (&E2)[32], __fp16* qsh, int j) {
  unsigned long long bal = __ballot(mreg != 0);
  if (bal == ~0ull) {                   // fast path: all 8 steps active
    float xs[8];
#pragma unroll
    for (int t = 0; t < 8; ++t) xs[t] = __expf(buf[t]);
#pragma unroll
    for (int t = 0; t < 8; ++t) crf_step(q, esum, xs[t], E2, qsh, j);
    nsteps += 8;
  } else if (bal != 0ull) {             // partial: per-step uniform branch
#pragma unroll
    for (int t = 0; t < 8; ++t) {
      int mv = __builtin_amdgcn_readlane(mreg, t);
      if (mv) {
        crf_step(q, esum, __expf(buf[t]), E2, qsh, j);
        nsteps += 1;
      }
    }
  }                                     // bal==0: fully dead block, skip
}

__global__ __launch_bounds__(64, 4) void crf_kernel(
    const float* __restrict__ em, const float* __restrict__ startT,
    const float* __restrict__ endT, const float* __restrict__ trans,
    const int* __restrict__ tags, const int* __restrict__ mask,
    float* __restrict__ out) {
  __shared__ alignas(16) __fp16 qsh[TT];
  const int b = blockIdx.x >> 4;        // batch
  const int c = blockIdx.x & (KC - 1);  // chunk
  const int j = threadIdx.x;            // tag (one wave per block)

  half2v E2[32];
#pragma unroll
  for (int m = 0; m < 32; ++m) {
    float e0 = __expf(trans[(2 * m) * TT + j]) * 0.03125f;
    float e1 = __expf(trans[(2 * m + 1) * TT + j]) * 0.03125f;
    E2[m] = __builtin_amdgcn_cvt_pkrtz(e0, e1);
  }

  const float* emb = em + (size_t)b * SS * TT;
  const float* ep = emb + j;
  const int* mp = mask + b * SS;
  const int* tg = tags + b * SS;

  float q, gamma_c0 = 0.f, pnum = 0.f;
  if (c == 0) {                         // exact init from alpha_0
    float a0v = startT[j] + ep[0];
    float a00 = rfl_f(a0v);
    q = __expf(a0v - a00) * 0.015625f;
    gamma_c0 = a00 * 1.4426950408889634f;
    int tg0 = tg[0];
    if (j == 0) pnum = startT[tg0] + emb[tg0];
  } else {
    q = 0.015625f;                      // uniform start; warmup fixes direction
  }
  qsh[j] = (__fp16)q;
  int esum = 0, nsteps = 0, nsteps0 = 0;
  float sS = 0.f;                       // scale at main start (c=0: absolute 0)

  // block t covers steps base+8t .. base+8t+7; t=0..5 warmup, t=6..21 main.
  const int base = c * LC - WARM + 1;
  const int t0 = (c == 0) ? 6 : 0;      // chunk 0 has no warmup

  float bufA[8], bufB[8];
  int mA, mB;
  float tvA, evA, tvB, evB;
  prefetch8(bufA, mA, tvA, evA, base + 8 * t0, t0 >= 6, ep, emb, mp, tg, trans, j);
  for (int t = t0; t < 22; t += 2) {
    prefetch8(bufB, mB, tvB, evB, base + 8 * (t + 1), t + 1 >= 6, ep, emb, mp, tg, trans, j);
    if (t == 6 && c != 0) {             // capture scale after warmup
      sS = __log2f(rfl_f(q)) + (float)(6 + esum - 116 * nsteps);
      nsteps0 = nsteps;
    }
    process8(q, esum, nsteps, bufA, mA, E2, qsh, j);
    pnum += (mA != 0) ? (tvA + evA) : 0.f;  // warmup blocks carry zeros
    prefetch8(bufA, mA, tvA, evA, base + 8 * (t + 2), t + 2 >= 6, ep, emb, mp, tg, trans, j);
    process8(q, esum, nsteps, bufB, mB, E2, qsh, j);
    pnum += (mB != 0) ? (tvB + evB) : 0.f;
  }

  // chunk contribution: V_c = log-scale growth over the main range
  float v_end = rfl_f(q);
  float eS = __log2f(v_end) + (float)(6 + esum - 116 * nsteps) + gamma_c0;
  float contrib = 0.69314718055994531f * (eS - sS);

  if (c == KC - 1) {                    // final logsumexp + numerator end term
    float arel = 0.69314718055994531f * (__log2f(q) - __log2f(v_end)) + endT[j];
    float mx = arel;
#pragma unroll
    for (int o = 32; o > 0; o >>= 1) mx = fmaxf(mx, __shfl_xor(mx, o, 64));
    float ex = __expf(arel - mx);
#pragma unroll
    for (int o = 32; o > 0; o >>= 1) ex += __shfl_xor(ex, o, 64);
    contrib += mx + __logf(ex);
    int lastTag = tg[c * LC + (nsteps - nsteps0)];  // global seq_end index
    contrib -= endT[lastTag];
  }

  // numerator partial (lanes 0-7 + lane0 step-0 term)
  float nsum = pnum;
#pragma unroll
  for (int o = 32; o > 0; o >>= 1) nsum += __shfl_xor(nsum, o, 64);

  if (j == 0) atomicAdd(out, (contrib - nsum) * (1.0f / BB));
}

extern "C" void kernel_launch(void* const* d_in, const int* in_sizes, int n_in,
                              void* d_out, int out_size, void* d_ws, size_t ws_size,
                              hipStream_t stream) {
  const float* em = (const float*)d_in[0];
  const float* startT = (const float*)d_in[1];
  const float* endT = (const float*)d_in[2];
  const float* trans = (const float*)d_in[3];
  const int* tags = (const int*)d_in[4];
  const int* mask = (const int*)d_in[5];
  float* out = (float*)d_out;

  (void)hipMemsetAsync(out, 0, sizeof(float), stream);
  crf_kernel<<<BB * KC, 64, 0, stream>>>(em, startT, endT, trans, tags, mask, out);
}